// Round 6
// baseline (637.791 us; speedup 1.0000x reference)
//
#include <hip/hip_runtime.h>
#include <stdint.h>

// CrossAttention, fp32/bf16 I/O autodetect, all-bf16 MFMA pipeline.
// R11: the five slow dispatches (identical FETCH=147.5MB) are the thin-weight
// GEMMs (L1,L4,q,k,vt) at 435 TF with 4.3x HBM over-fetch: 256x256 tiles
// force 4-block sharing of streamed A panels, which L2 does not deliver;
// full-rate would need 6.6 TB/s (>6.3 achievable). Fix: gemm_bt5 = 128x512
// tile (streamed operand 8KB/K-tile fetched once per block -> 1.65 TB/s at
// full rate, no inter-block reuse required; 2MB weight is the L2-resident
// operand). vt GEMM replaced by v-GEMM (bt5) + cheap 32x32 transpose.
// scores/PV keep the proven R10 gemm8; L2(N=512)+fallback keep gemm_bt.

typedef __attribute__((ext_vector_type(8))) short bf16x8;
typedef __attribute__((ext_vector_type(4))) float f32x4;
typedef __attribute__((ext_vector_type(8))) unsigned short u16x8;

__device__ __forceinline__ float bf2f(unsigned short u) {
    return __uint_as_float(((unsigned int)u) << 16);
}
__device__ __forceinline__ unsigned short f2bf(float f) {
    unsigned int u = __float_as_uint(f);
    unsigned int r = (u + 0x7fffu + ((u >> 16) & 1u)) >> 16;
    return (unsigned short)r;
}

__device__ __forceinline__ void async16(const void* g, void* l) {
    __builtin_amdgcn_global_load_lds(
        (const __attribute__((address_space(1))) unsigned int*)g,
        (__attribute__((address_space(3))) unsigned int*)l,
        16, 0, 0);
}

// ---------------------------------------------------------------------------
__global__ __launch_bounds__(64) void detect_dtype(
    const unsigned short* __restrict__ w, int* __restrict__ flag)
{
    const int t = threadIdx.x;
    int cnt = 0;
    for (int i = t; i < 4096; i += 64) {
        const unsigned e = (w[i] >> 7) & 0xFF;
        cnt += (e >= 140) ? 1 : 0;
    }
#pragma unroll
    for (int off = 32; off; off >>= 1) cnt += __shfl_xor(cnt, off, 64);
    if (t == 0) flag[0] = (cnt >= 8) ? 1 : 0;
}

// ---------------------------------------------------------------------------
__global__ __launch_bounds__(256) void conv_bias_all(
    const void* b1, const void* b2, const void* b3, const void* b4,
    const void* bq, const void* bk, const void* bv,
    float* __restrict__ out, const int* __restrict__ flag)
{
    const int i = blockIdx.x * 256 + threadIdx.x;
    const int slot = i >> 10, idx = i & 1023;
    if (slot == 1 && idx >= 512) return;
    const void* src = (slot == 0) ? b1 : (slot == 1) ? b2 : (slot == 2) ? b3 :
                      (slot == 3) ? b4 : (slot == 4) ? bq : (slot == 5) ? bk : bv;
    out[i] = (*flag) ? ((const float*)src)[idx]
                     : bf2f(((const unsigned short*)src)[idx]);
}

// ---------------------------------------------------------------------------
__device__ __forceinline__ void wt_body(
    const void* in, unsigned short* out, int R, int C, int f)
{
    __shared__ unsigned short tile[32][33];
    const int bc = blockIdx.x * 32;
    const int br = blockIdx.y * 32;
    const int x = threadIdx.x & 31;
    const int y = threadIdx.x >> 5;
#pragma unroll
    for (int i = 0; i < 4; i++) {
        const int r = y + i * 8;
        unsigned short v;
        if (f) v = f2bf(((const float*)in)[(size_t)(br + r) * C + bc + x]);
        else   v = ((const unsigned short*)in)[(size_t)(br + r) * C + bc + x];
        tile[r][x] = v;
    }
    __syncthreads();
#pragma unroll
    for (int i = 0; i < 4; i++) {
        const int r = y + i * 8;
        out[(size_t)(bc + r) * R + br + x] = tile[x][r];
    }
}

__global__ __launch_bounds__(256) void conv_weight_t7(
    const void* i0, unsigned short* o0, const void* i1, unsigned short* o1,
    const void* i2, unsigned short* o2, const void* i3, unsigned short* o3,
    const void* i4, unsigned short* o4, const void* i5, unsigned short* o5,
    const void* i6, unsigned short* o6, const int* flag)
{
    const int z = blockIdx.z;
    if (z == 5) {
        if (blockIdx.x >= 16) return;
        wt_body(i5, o5, 1024, 512, *flag);
        return;
    }
    if (z == 6) {
        if (blockIdx.y >= 16) return;
        wt_body(i6, o6, 512, 1024, *flag);
        return;
    }
    const void* in = (z == 0) ? i0 : (z == 1) ? i1 : (z == 2) ? i2 : (z == 3) ? i3 : i4;
    unsigned short* out = (z == 0) ? o0 : (z == 1) ? o1 : (z == 2) ? o2 : (z == 3) ? o3 : o4;
    wt_body(in, out, 1024, 1024, *flag);
}

// bf16 [R][C] -> [C][R] transpose, z-batched (stride R*C both sides)
__global__ __launch_bounds__(256) void transpose_bf16(
    const unsigned short* __restrict__ in, unsigned short* __restrict__ out,
    int R, int C)
{
    __shared__ unsigned short tile[32][33];
    const size_t zofs = (size_t)blockIdx.z * R * C;
    const unsigned short* ip = in + zofs;
    unsigned short* op = out + zofs;
    const int bc = blockIdx.x * 32;
    const int br = blockIdx.y * 32;
    const int x = threadIdx.x & 31;
    const int y = threadIdx.x >> 5;
#pragma unroll
    for (int i = 0; i < 4; i++) {
        const int r = y + i * 8;
        tile[r][x] = ip[(size_t)(br + r) * C + bc + x];
    }
    __syncthreads();
#pragma unroll
    for (int i = 0; i < 4; i++) {
        const int r = y + i * 8;
        op[(size_t)(bc + r) * R + br + x] = tile[x][r];
    }
}

__global__ __launch_bounds__(256) void conv_to_bf16(
    const void* __restrict__ in, unsigned short* __restrict__ out,
    int n, const int* __restrict__ flag)
{
    const int i = (blockIdx.x * 256 + threadIdx.x) * 8;
    if (i >= n) return;
    if (*flag) {
        const float4* p = (const float4*)((const float*)in + i);
        const float4 a = p[0], b = p[1];
        u16x8 o;
        o[0] = f2bf(a.x); o[1] = f2bf(a.y); o[2] = f2bf(a.z); o[3] = f2bf(a.w);
        o[4] = f2bf(b.x); o[5] = f2bf(b.y); o[6] = f2bf(b.z); o[7] = f2bf(b.w);
        *(u16x8*)(out + i) = o;
    } else {
        *(u16x8*)(out + i) = *(const u16x8*)((const unsigned short*)in + i);
    }
}

__global__ __launch_bounds__(256) void write_out(
    const unsigned short* __restrict__ src, void* __restrict__ dst,
    int n, const int* __restrict__ flag)
{
    const int i = (blockIdx.x * 256 + threadIdx.x) * 8;
    if (i >= n) return;
    const u16x8 v = *(const u16x8*)(src + i);
    if (*flag) {
        float4 a, b;
        a.x = bf2f(v[0]); a.y = bf2f(v[1]); a.z = bf2f(v[2]); a.w = bf2f(v[3]);
        b.x = bf2f(v[4]); b.y = bf2f(v[5]); b.z = bf2f(v[6]); b.w = bf2f(v[7]);
        float4* p = (float4*)((float*)dst + i);
        p[0] = a; p[1] = b;
    } else {
        *(u16x8*)((unsigned short*)dst + i) = v;
    }
}

// ---------------------------------------------------------------------------
// Proven 128x128 GEMM: kept for L2 (N=512) and the fallback path.
// ---------------------------------------------------------------------------
template <int RELU, int BIAS, int OUTF, int SWZ>
__global__ __launch_bounds__(256, 2) void gemm_bt(
    const unsigned short* __restrict__ A, const unsigned short* __restrict__ B,
    const float* __restrict__ bias, void* __restrict__ C,
    int M, int N, int K, float alpha,
    long long sA, long long sB, long long sC, const int* __restrict__ flag)
{
    int bxi = blockIdx.x, byi = blockIdx.y;
    if (SWZ) {
        const int id = byi * gridDim.x + bxi;
        bxi = (id >> 3) % gridDim.x;
        byi = (id >> 3) / gridDim.x * 8 + (id & 7);
    }
    const int z = blockIdx.z;
    A += (size_t)z * (size_t)sA;
    B += (size_t)z * (size_t)sB;
    const size_t cofs = (size_t)z * (size_t)sC;

    const int bm = byi * 128;
    const int bn = bxi * 128;
    const int t = threadIdx.x;
    const int lane = t & 63;
    const int w = t >> 6;
    const int wr = (w >> 1) * 64;
    const int wc = (w & 1) * 64;

    __shared__ unsigned short sAt[128 * 32];
    __shared__ unsigned short sBt[128 * 32];

    f32x4 acc[4][4];
#pragma unroll
    for (int i = 0; i < 4; i++)
#pragma unroll
        for (int j = 0; j < 4; j++)
            acc[i][j] = (f32x4){0.f, 0.f, 0.f, 0.f};

    const int tr = t >> 2;
    const int tc = (t & 3) << 3;
    const unsigned short* ga = A + (size_t)(bm + tr) * K + tc;
    const unsigned short* gb = B + (size_t)(bn + tr) * K + tc;
    unsigned short* la = &sAt[tr * 32 + tc];
    unsigned short* lb = &sBt[tr * 32 + tc];

    const int am = wr + (lane & 15);
    const int bn_ = wc + (lane & 15);
    const int ak = (lane >> 4) * 8;

    for (int k0 = 0; k0 < K; k0 += 32) {
        async16(ga, la);
        async16(ga + (size_t)64 * K, la + 64 * 32);
        async16(gb, lb);
        async16(gb + (size_t)64 * K, lb + 64 * 32);
        ga += 32;
        gb += 32;
        __syncthreads();

        bf16x8 af[4], bfr[4];
#pragma unroll
        for (int i = 0; i < 4; i++)
            af[i] = *(const bf16x8*)&sAt[(am + i * 16) * 32 + ak];
#pragma unroll
        for (int j = 0; j < 4; j++)
            bfr[j] = *(const bf16x8*)&sBt[(bn_ + j * 16) * 32 + ak];
#pragma unroll
        for (int i = 0; i < 4; i++)
#pragma unroll
            for (int j = 0; j < 4; j++)
                acc[i][j] = __builtin_amdgcn_mfma_f32_16x16x32_bf16(
                    af[i], bfr[j], acc[i][j], 0, 0, 0);
        __syncthreads();
    }

    const int fl = OUTF ? *flag : 0;
#pragma unroll
    for (int i = 0; i < 4; i++) {
        const int row0 = bm + wr + i * 16 + (lane >> 4) * 4;
#pragma unroll
        for (int j = 0; j < 4; j++) {
            const int col = bn + wc + j * 16 + (lane & 15);
            float bc = 0.f;
            if (BIAS == 1) bc = bias[col];
#pragma unroll
            for (int r = 0; r < 4; r++) {
                float bv = bc;
                if (BIAS == 2) bv = bias[row0 + r];
                float vv = acc[i][j][r] * alpha + bv;
                if (RELU) vv = fmaxf(vv, 0.f);
                const size_t idx = cofs + (size_t)(row0 + r) * N + col;
                if (OUTF && fl) ((float*)C)[idx] = vv;
                else ((unsigned short*)C)[idx] = f2bf(vv);
            }
        }
    }
}

// ---------------------------------------------------------------------------
// R10 gemm8 (proven): 256x256 tile, BK=32, 4 slots, 1 barrier/K-tile.
// Kept for scores (both operands shared 8-way) and PV.
// ---------------------------------------------------------------------------
#define G10_STG(SOFS, KOFS) do {                                               \
    async16(gAs + (KOFS), dA + (SOFS));                                        \
    async16(gAs + (KOFS) + rk128, dA + (SOFS) + 4096);                         \
    async16(gBs + (KOFS), dB + (SOFS));                                        \
    async16(gBs + (KOFS) + rk128, dB + (SOFS) + 4096);                         \
} while (0)

template <int RELU, int BIAS, int OUTF, int SWZ>
__global__ __launch_bounds__(512, 2) void gemm8(
    const unsigned short* __restrict__ A, const unsigned short* __restrict__ B,
    const float* __restrict__ bias, void* __restrict__ C,
    int M, int N, int K, float alpha,
    long long sA, long long sB, long long sC, const int* __restrict__ flag)
{
    extern __shared__ unsigned short lds[];
    (void)M;
    int bxi = blockIdx.x, byi = blockIdx.y;
    if (SWZ) {
        const int id = byi * gridDim.x + bxi;
        bxi = (id >> 3) % gridDim.x;
        byi = (id >> 3) / gridDim.x * 8 + (id & 7);
    }
    const int z = blockIdx.z;
    A += (size_t)z * (size_t)sA;
    B += (size_t)z * (size_t)sB;
    const size_t cofs = (size_t)z * (size_t)sC;

    const int bm = byi * 256;
    const int bn = bxi * 256;
    const int t = threadIdx.x;
    const int lane = t & 63;
    const int w = t >> 6;
    const int wm = w >> 2;
    const int wn = w & 3;

    const int soct = ((t & 3) ^ ((t >> 3) & 3)) << 3;
    const unsigned short* gAs = A + (size_t)(bm + (t >> 2)) * K + soct;
    const unsigned short* gBs = B + (size_t)(bn + (t >> 2)) * K + soct;
    const size_t rk128 = (size_t)128 * K;
    unsigned short* dA = lds + t * 8;
    unsigned short* dB = lds + 32768 + t * 8;

    const int l15 = lane & 15;
    const int oct = (((lane >> 4) ^ ((lane >> 1) & 3)) << 3);
    const int aoff = (wm * 128 + l15) * 32 + oct;
    const int boff = (wn * 64 + l15) * 32 + oct;

    f32x4 acc[8][4];
#pragma unroll
    for (int i = 0; i < 8; i++)
#pragma unroll
        for (int j = 0; j < 4; j++)
            acc[i][j] = (f32x4){0.f, 0.f, 0.f, 0.f};

    G10_STG(0, 0);
    G10_STG(8192, 32);
    asm volatile("s_waitcnt vmcnt(4)" ::: "memory");
    __builtin_amdgcn_s_barrier();
    asm volatile("" ::: "memory");

    const int NT = K >> 5;
    for (int T = 0; T < NT; ++T) {
        if (T + 2 < NT) {
            const int so = ((T + 2) & 3) * 8192;
            const int ko = (T + 2) << 5;
            G10_STG(so, ko);
        }
        const int sr = (T & 3) * 8192;
        const unsigned short* pa = lds + sr + aoff;
        const unsigned short* pb = lds + 32768 + sr + boff;
        bf16x8 bb[4], a[8];
#pragma unroll
        for (int n = 0; n < 4; n++)
            bb[n] = *(const bf16x8*)(pb + n * 512);
#pragma unroll
        for (int m = 0; m < 8; m++)
            a[m] = *(const bf16x8*)(pa + m * 512);
        __builtin_amdgcn_s_setprio(1);
#pragma unroll
        for (int m = 0; m < 8; m++)
#pragma unroll
            for (int n = 0; n < 4; n++)
                acc[m][n] = __builtin_amdgcn_mfma_f32_16x16x32_bf16(
                    a[m], bb[n], acc[m][n], 0, 0, 0);
        __builtin_amdgcn_s_setprio(0);
        if (T + 1 < NT) {
            if (T + 2 < NT) {
                asm volatile("s_waitcnt vmcnt(4)" ::: "memory");
            } else {
                asm volatile("s_waitcnt vmcnt(0)" ::: "memory");
            }
            __builtin_amdgcn_s_barrier();
            asm volatile("" ::: "memory");
        }
    }

    const int fl = OUTF ? *flag : 0;
#pragma unroll
    for (int mi = 0; mi < 8; mi++) {
        const int row0 = bm + wm * 128 + mi * 16 + (lane >> 4) * 4;
#pragma unroll
        for (int n = 0; n < 4; n++) {
            const int col = bn + wn * 64 + n * 16 + (lane & 15);
            float bc = 0.f;
            if (BIAS == 1) bc = bias[col];
#pragma unroll
            for (int r = 0; r < 4; r++) {
                float bv = bc;
                if (BIAS == 2) bv = bias[row0 + r];
                float vv = acc[mi][n][r] * alpha + bv;
                if (RELU) vv = fmaxf(vv, 0.f);
                const size_t idx = cofs + (size_t)(row0 + r) * N + col;
                if (OUTF && fl) ((float*)C)[idx] = vv;
                else ((unsigned short*)C)[idx] = f2bf(vv);
            }
        }
    }
}

// ---------------------------------------------------------------------------
// R11 gemm_bt5: 128(m) x 512(n) tile, BK=32, 8 waves (2m x 4n, wave 64x128),
// 3 LDS slots of {A 8KB + B 32KB} = 120 KiB. Same loop/swizzle as gemm8-R10
// (HW-verified: bank-conflict 0), 5 loads/K-tile (A x1, B x4), vmcnt(5).
// Streamed A fetched once per block (no inter-block L2 reuse needed);
// B = 2MB weight panel, L2-resident. M%128==0, N%512==0, K%32==0, K>=96.
// ---------------------------------------------------------------------------
template <int RELU, int BIAS, int OUTF, int SWZ>
__global__ __launch_bounds__(512, 2) void gemm_bt5(
    const unsigned short* __restrict__ A, const unsigned short* __restrict__ B,
    const float* __restrict__ bias, void* __restrict__ C,
    int M, int N, int K, float alpha,
    long long sA, long long sB, long long sC, const int* __restrict__ flag)
{
    extern __shared__ unsigned short lds[];
    (void)M;
    int bxi = blockIdx.x, byi = blockIdx.y;
    if (SWZ) {
        const int id = byi * gridDim.x + bxi;
        bxi = (id >> 3) % gridDim.x;
        byi = (id >> 3) / gridDim.x * 8 + (id & 7);
    }
    const int z = blockIdx.z;
    A += (size_t)z * (size_t)sA;
    B += (size_t)z * (size_t)sB;
    const size_t cofs = (size_t)z * (size_t)sC;

    const int bm = byi * 128;
    const int bn = bxi * 512;
    const int t = threadIdx.x;
    const int lane = t & 63;
    const int w = t >> 6;
    const int wm = w >> 2;   // 0..1 : 64 output rows each
    const int wn = w & 3;    // 0..3 : 128 output cols each

    // staging: linear LDS dest, inverse-swizzled global source (R10 scheme)
    const int soct = ((t & 3) ^ ((t >> 3) & 3)) << 3;
    const unsigned short* gAs = A + (size_t)(bm + (t >> 2)) * K + soct;
    const unsigned short* gBs = B + (size_t)(bn + (t >> 2)) * K + soct;
    const size_t rk128 = (size_t)128 * K;
    unsigned short* dA = lds + t * 8;            // A slots: + s*4096
    unsigned short* dB = lds + 12288 + t * 8;    // B slots: + s*16384

    // swizzled ds_read offsets (R10 scheme, conflict-free verified)
    const int l15 = lane & 15;
    const int oct = (((lane >> 4) ^ ((lane >> 1) & 3)) << 3);
    const int aoff = (wm * 64 + l15) * 32 + oct;
    const int boff = (wn * 128 + l15) * 32 + oct;

    f32x4 acc[4][8];
#pragma unroll
    for (int i = 0; i < 4; i++)
#pragma unroll
        for (int j = 0; j < 8; j++)
            acc[i][j] = (f32x4){0.f, 0.f, 0.f, 0.f};

    // prologue: tile0 -> slot0, tile1 -> slot1 (5 loads each); drain tile0.
    async16(gAs, dA);
    async16(gBs, dB);
    async16(gBs + rk128, dB + 4096);
    async16(gBs + 2 * rk128, dB + 8192);
    async16(gBs + 3 * rk128, dB + 12288);
    async16(gAs + 32, dA + 4096);
    async16(gBs + 32, dB + 16384);
    async16(gBs + 32 + rk128, dB + 16384 + 4096);
    async16(gBs + 32 + 2 * rk128, dB + 16384 + 8192);
    async16(gBs + 32 + 3 * rk128, dB + 16384 + 12288);
    asm volatile("s_waitcnt vmcnt(5)" ::: "memory");
    __builtin_amdgcn_s_barrier();
    asm volatile("" ::: "memory");

    const int NT = K >> 5;
    int rs = 0, ws = 2;                  // read slot = T%3, write slot = (T+2)%3
    for (int T = 0; T < NT; ++T) {
        if (T + 2 < NT) {
            const int ko = (T + 2) << 5;
            const int wa = ws * 4096;
            const int wb = ws * 16384;
            async16(gAs + ko, dA + wa);
            async16(gBs + ko, dB + wb);
            async16(gBs + ko + rk128, dB + wb + 4096);
            async16(gBs + ko + 2 * rk128, dB + wb + 8192);
            async16(gBs + ko + 3 * rk128, dB + wb + 12288);
        }
        const unsigned short* pa = lds + rs * 4096 + aoff;
        const unsigned short* pb = lds + 12288 + rs * 16384 + boff;
        bf16x8 a[4], bb[8];
#pragma unroll
        for (int m = 0; m < 4; m++)
            a[m] = *(const bf16x8*)(pa + m * 512);
#pragma unroll
        for (int n = 0; n < 8; n++)
            bb[n] = *(const bf16x8*)(pb + n * 512);
        __builtin_amdgcn_s_setprio(1);
#pragma unroll
        for (int m = 0; m < 4; m++)
#pragma unroll
            for (int n = 0; n < 8; n++)
                acc[m][n] = __builtin_amdgcn_mfma_f32_16x16x32_bf16(
                    a[m], bb[n], acc[m][n], 0, 0, 0);
        __builtin_amdgcn_s_setprio(0);
        if (T + 1 < NT) {
            if (T + 2 < NT) {
                asm volatile("s_waitcnt vmcnt(5)" ::: "memory");
            } else {
                asm volatile("s_waitcnt vmcnt(0)" ::: "memory");
            }
            __builtin_amdgcn_s_barrier();
            asm volatile("" ::: "memory");
        }
        rs = (rs == 2) ? 0 : rs + 1;
        ws = (ws == 2) ? 0 : ws + 1;
    }

    const int fl = OUTF ? *flag : 0;
#pragma unroll
    for (int mi = 0; mi < 4; mi++) {
        const int row0 = bm + wm * 64 + mi * 16 + (lane >> 4) * 4;
#pragma unroll
        for (int n = 0; n < 8; n++) {
            const int col = bn + wn * 128 + n * 16 + (lane & 15);
            float bc = 0.f;
            if (BIAS == 1) bc = bias[col];
#pragma unroll
            for (int r = 0; r < 4; r++) {
                float bv = bc;
                if (BIAS == 2) bv = bias[row0 + r];
                float vv = acc[mi][n][r] * alpha + bv;
                if (RELU) vv = fmaxf(vv, 0.f);
                const size_t idx = cofs + (size_t)(row0 + r) * N + col;
                if (OUTF && fl) ((float*)C)[idx] = vv;
                else ((unsigned short*)C)[idx] = f2bf(vv);
            }
        }
    }
}

// ---------------------------------------------------------------------------
__global__ __launch_bounds__(256) void softmax_rows(unsigned short* S, int n)
{
    const size_t row = blockIdx.x;
    unsigned short* p = S + row * (size_t)n;
    const int t = threadIdx.x;
    const int lane = t & 63;
    const int wave = t >> 6;

    u16x8 v = *(const u16x8*)(p + t * 8);
    float f[8];
    float m = -3.0e38f;
#pragma unroll
    for (int i = 0; i < 8; i++) {
        f[i] = bf2f(v[i]);
        m = fmaxf(m, f[i]);
    }
#pragma unroll
    for (int off = 32; off; off >>= 1) m = fmaxf(m, __shfl_xor(m, off, 64));
    __shared__ float redm[4];
    if (lane == 0) redm[wave] = m;
    __syncthreads();
    m = fmaxf(fmaxf(redm[0], redm[1]), fmaxf(redm[2], redm[3]));

    float e[8];
    float s = 0.f;
#pragma unroll
    for (int i = 0; i < 8; i++) {
        e[i] = __expf(f[i] - m);
        s += e[i];
    }
#pragma unroll
    for (int off = 32; off; off >>= 1) s += __shfl_xor(s, off, 64);
    __shared__ float reds[4];
    if (lane == 0) reds[wave] = s;
    __syncthreads();
    s = reds[0] + reds[1] + reds[2] + reds[3];
    const float inv = 1.0f / s;

    u16x8 o;
#pragma unroll
    for (int i = 0; i < 8; i++) o[i] = f2bf(e[i] * inv);
    *(u16x8*)(p + t * 8) = o;
}

// ---------------------------------------------------------------------------
extern "C" void kernel_launch(void* const* d_in, const int* in_sizes, int n_in,
                              void* d_out, int out_size, void* d_ws, size_t ws_size,
                              hipStream_t stream)
{
    const void* x  = d_in[0];
    const void* y  = d_in[1];
    const void* W1 = d_in[2];
    const void* b1 = d_in[3];
    const void* W2 = d_in[4];
    const void* b2 = d_in[5];
    const void* W3 = d_in[6];
    const void* b3 = d_in[7];
    const void* W4 = d_in[8];
    const void* b4 = d_in[9];
    const void* Wq = d_in[10];
    const void* bq = d_in[11];
    const void* Wk = d_in[12];
    const void* bk = d_in[13];
    const void* Wv = d_in[14];
    const void* bv = d_in[15];

    int* flag = (int*)d_ws;
    float* fb = (float*)((char*)d_ws + 64);
    unsigned short* arena = (unsigned short*)((char*)d_ws + 64 + 7 * 1024 * 4);
    const size_t baseB = 64 + 7 * 1024 * 4;
    const size_t MEG = 1024ull * 1024ull;

    auto needB = [&](int G, bool direct) -> size_t {
        return baseB + 2ull * ((6 + 16 + (size_t)G * 6 + (direct ? 0 : 16)) * MEG);
    };
    int G; bool direct;
    if (ws_size >= needB(8, true))      { G = 8; direct = true;  }
    else if (ws_size >= needB(4, false)) { G = 4; direct = false; }
    else if (ws_size >= needB(2, false)) { G = 2; direct = false; }
    else                                 { G = 1; direct = false; }

    unsigned short* W1t = arena;
    unsigned short* W2t = W1t + 1 * MEG;
    unsigned short* W3t = W2t + MEG / 2;
    unsigned short* W4t = W3t + MEG / 2;
    unsigned short* Wqt = W4t + 1 * MEG;
    unsigned short* Wkt = Wqt + 1 * MEG;
    unsigned short* Wvt = Wkt + 1 * MEG;
    unsigned short* XC  = Wvt + 1 * MEG;
    unsigned short* VT  = XC + 16 * MEG;
    unsigned short* SBUF = VT + (size_t)G * 2 * MEG;
    unsigned short* OUTS = SBUF + (size_t)G * 4 * MEG;

    unsigned short* PA = (unsigned short*)d_out;
    unsigned short* PB = PA + 16 * MEG;

    float* fb1 = fb;
    float* fb2 = fb + 1024;
    float* fb3 = fb + 2048;
    float* fb4 = fb + 3072;
    float* fbq = fb + 4096;
    float* fbk = fb + 5120;
    float* fbv = fb + 6144;

    const dim3 blk(256);
    const dim3 blk8(512);
    const int LDS8 = 131072;
    const int LDS5 = 122880;
    const int NE = 16 * 1024 * 1024;
    const int Mx = 16384;
    const long long Z0 = 0;
    const long long sQK = 2048ll * 1024;
    const long long sS  = 2048ll * 2048;

    (void)hipFuncSetAttribute((const void*)&gemm_bt5<1, 1, 0, 1>,
                              hipFuncAttributeMaxDynamicSharedMemorySize, LDS5);
    (void)hipFuncSetAttribute((const void*)&gemm_bt5<0, 1, 0, 1>,
                              hipFuncAttributeMaxDynamicSharedMemorySize, LDS5);
    (void)hipFuncSetAttribute((const void*)&gemm8<0, 0, 0, 1>,
                              hipFuncAttributeMaxDynamicSharedMemorySize, LDS8);
    (void)hipFuncSetAttribute((const void*)&gemm8<0, 0, 1, 1>,
                              hipFuncAttributeMaxDynamicSharedMemorySize, LDS8);

    detect_dtype<<<1, 64, 0, stream>>>((const unsigned short*)W1, flag);
    conv_bias_all<<<28, blk, 0, stream>>>(b1, b2, b3, b4, bq, bk, bv, fb, flag);
    conv_weight_t7<<<dim3(32, 32, 7), blk, 0, stream>>>(
        W1, W1t, W4, W4t, Wq, Wqt, Wk, Wkt, Wv, Wvt, W2, W2t, W3, W3t, flag);

    conv_to_bf16<<<8192, blk, 0, stream>>>(x, XC, NE, flag);

    // MLP: L1/L3/L4 on gemm_bt5 (128x512), L2 (N=512) on proven gemm_bt
    gemm_bt5<1, 1, 0, 1><<<dim3(2, 128), blk8, LDS5, stream>>>(
        XC, W1t, fb1, PA, Mx, 1024, 1024, 1.f, Z0, Z0, Z0, flag);
    gemm_bt<1, 1, 0, 1><<<dim3(4, 128), blk, 0, stream>>>(
        PA, W2t, fb2, PB, Mx, 512, 1024, 1.f, Z0, Z0, Z0, flag);
    gemm_bt5<1, 1, 0, 1><<<dim3(2, 128), blk8, LDS5, stream>>>(
        PB, W3t, fb3, PA, Mx, 1024, 512, 1.f, Z0, Z0, Z0, flag);
    gemm_bt5<1, 1, 0, 1><<<dim3(2, 128), blk8, LDS5, stream>>>(
        PA, W4t, fb4, PB, Mx, 1024, 1024, 1.f, Z0, Z0, Z0, flag);

    // q -> PA ; y -> XC ; k -> PB
    gemm_bt5<0, 1, 0, 1><<<dim3(2, 128), blk8, LDS5, stream>>>(
        PB, Wqt, fbq, PA, Mx, 1024, 1024, 1.f, Z0, Z0, Z0, flag);
    conv_to_bf16<<<8192, blk, 0, stream>>>(y, XC, NE, flag);
    gemm_bt5<0, 1, 0, 1><<<dim3(2, 128), blk8, LDS5, stream>>>(
        XC, Wkt, fbk, PB, Mx, 1024, 1024, 1.f, Z0, Z0, Z0, flag);

    if (direct) {
        // v = y@Wv + bv (same shape/rate as k), then cheap transpose -> VT
        gemm_bt5<0, 1, 0, 1><<<dim3(2, 128), blk8, LDS5, stream>>>(
            XC, Wvt, fbv, SBUF, Mx, 1024, 1024, 1.f, Z0, Z0, Z0, flag);
        transpose_bf16<<<dim3(32, 64, 8), blk, 0, stream>>>(SBUF, VT, 2048, 1024);
        gemm8<0, 0, 0, 1><<<dim3(8, 8, 8), blk8, LDS8, stream>>>(
            PA, PB, nullptr, SBUF, 2048, 2048, 1024, 0.03125f, sQK, sQK, sS, flag);
        softmax_rows<<<dim3(8 * 2048), blk, 0, stream>>>(SBUF, 2048);
        gemm8<0, 0, 1, 1><<<dim3(4, 8, 8), blk8, LDS8, stream>>>(
            SBUF, VT, nullptr, d_out, 2048, 1024, 2048, 1.f, sS, sQK, sQK, flag);
    } else {
        for (int g = 0; g < 8; g += G) {
            const size_t off = (size_t)g * 2048 * 1024;
            gemm_bt<0, 2, 0, 0><<<dim3(16, 8, G), blk, 0, stream>>>(
                Wvt, XC + off, fbv, VT, 1024, 2048, 1024, 1.f, Z0, sQK, sQK, flag);
            gemm_bt<0, 0, 0, 1><<<dim3(16, 16, G), blk, 0, stream>>>(
                PA + off, PB + off, nullptr, SBUF, 2048, 2048, 1024, 0.03125f, sQK, sQK, sS, flag);
            softmax_rows<<<dim3(G * 2048), blk, 0, stream>>>(SBUF, 2048);
            gemm_bt<0, 0, 0, 1><<<dim3(8, 16, G), blk, 0, stream>>>(
                SBUF, VT, nullptr, OUTS + off, 2048, 1024, 2048, 1.f, sS, sQK, sQK, flag);
        }
        write_out<<<8192, blk, 0, stream>>>(OUTS, d_out, NE, flag);
    }
}

// Round 7
// 630.325 us; speedup vs baseline: 1.0118x; 1.0118x over previous
//
#include <hip/hip_runtime.h>
#include <stdint.h>

// CrossAttention, fp32/bf16 I/O autodetect, all-bf16 MFMA pipeline.
// R12: revert R11 (bt5 + v-transpose regressed; top-5 were scores all
// along, WRITE=65.5MB signature). Base = R10 (603us). Single change:
// gemm8 SWZ=2 = batch->XCD swizzle for the 8-batch GEMMs (scores, PV,
// vt): hardware dispatches linear block id round-robin over 8 XCDs, so
// z = h&7 pins each batch to one XCD; within a batch, x-chunked y-major
// traversal keeps the k/V chunk L2-resident. Per-batch working set
// (8-12MB) ~fits the XCD's 4MB L2 chunk-wise -> scores fetch ~96MB vs
// 147.5 measured. Thin GEMMs / L2 / fallback unchanged from R10.

typedef __attribute__((ext_vector_type(8))) short bf16x8;
typedef __attribute__((ext_vector_type(4))) float f32x4;
typedef __attribute__((ext_vector_type(8))) unsigned short u16x8;

__device__ __forceinline__ float bf2f(unsigned short u) {
    return __uint_as_float(((unsigned int)u) << 16);
}
__device__ __forceinline__ unsigned short f2bf(float f) {
    unsigned int u = __float_as_uint(f);
    unsigned int r = (u + 0x7fffu + ((u >> 16) & 1u)) >> 16;
    return (unsigned short)r;
}

__device__ __forceinline__ void async16(const void* g, void* l) {
    __builtin_amdgcn_global_load_lds(
        (const __attribute__((address_space(1))) unsigned int*)g,
        (__attribute__((address_space(3))) unsigned int*)l,
        16, 0, 0);
}

// ---------------------------------------------------------------------------
__global__ __launch_bounds__(64) void detect_dtype(
    const unsigned short* __restrict__ w, int* __restrict__ flag)
{
    const int t = threadIdx.x;
    int cnt = 0;
    for (int i = t; i < 4096; i += 64) {
        const unsigned e = (w[i] >> 7) & 0xFF;
        cnt += (e >= 140) ? 1 : 0;
    }
#pragma unroll
    for (int off = 32; off; off >>= 1) cnt += __shfl_xor(cnt, off, 64);
    if (t == 0) flag[0] = (cnt >= 8) ? 1 : 0;
}

// ---------------------------------------------------------------------------
__global__ __launch_bounds__(256) void conv_bias_all(
    const void* b1, const void* b2, const void* b3, const void* b4,
    const void* bq, const void* bk, const void* bv,
    float* __restrict__ out, const int* __restrict__ flag)
{
    const int i = blockIdx.x * 256 + threadIdx.x;
    const int slot = i >> 10, idx = i & 1023;
    if (slot == 1 && idx >= 512) return;
    const void* src = (slot == 0) ? b1 : (slot == 1) ? b2 : (slot == 2) ? b3 :
                      (slot == 3) ? b4 : (slot == 4) ? bq : (slot == 5) ? bk : bv;
    out[i] = (*flag) ? ((const float*)src)[idx]
                     : bf2f(((const unsigned short*)src)[idx]);
}

// ---------------------------------------------------------------------------
__device__ __forceinline__ void wt_body(
    const void* in, unsigned short* out, int R, int C, int f)
{
    __shared__ unsigned short tile[32][33];
    const int bc = blockIdx.x * 32;
    const int br = blockIdx.y * 32;
    const int x = threadIdx.x & 31;
    const int y = threadIdx.x >> 5;
#pragma unroll
    for (int i = 0; i < 4; i++) {
        const int r = y + i * 8;
        unsigned short v;
        if (f) v = f2bf(((const float*)in)[(size_t)(br + r) * C + bc + x]);
        else   v = ((const unsigned short*)in)[(size_t)(br + r) * C + bc + x];
        tile[r][x] = v;
    }
    __syncthreads();
#pragma unroll
    for (int i = 0; i < 4; i++) {
        const int r = y + i * 8;
        out[(size_t)(bc + r) * R + br + x] = tile[x][r];
    }
}

__global__ __launch_bounds__(256) void conv_weight_t7(
    const void* i0, unsigned short* o0, const void* i1, unsigned short* o1,
    const void* i2, unsigned short* o2, const void* i3, unsigned short* o3,
    const void* i4, unsigned short* o4, const void* i5, unsigned short* o5,
    const void* i6, unsigned short* o6, const int* flag)
{
    const int z = blockIdx.z;
    if (z == 5) {
        if (blockIdx.x >= 16) return;
        wt_body(i5, o5, 1024, 512, *flag);
        return;
    }
    if (z == 6) {
        if (blockIdx.y >= 16) return;
        wt_body(i6, o6, 512, 1024, *flag);
        return;
    }
    const void* in = (z == 0) ? i0 : (z == 1) ? i1 : (z == 2) ? i2 : (z == 3) ? i3 : i4;
    unsigned short* out = (z == 0) ? o0 : (z == 1) ? o1 : (z == 2) ? o2 : (z == 3) ? o3 : o4;
    wt_body(in, out, 1024, 1024, *flag);
}

__global__ __launch_bounds__(256) void conv_to_bf16(
    const void* __restrict__ in, unsigned short* __restrict__ out,
    int n, const int* __restrict__ flag)
{
    const int i = (blockIdx.x * 256 + threadIdx.x) * 8;
    if (i >= n) return;
    if (*flag) {
        const float4* p = (const float4*)((const float*)in + i);
        const float4 a = p[0], b = p[1];
        u16x8 o;
        o[0] = f2bf(a.x); o[1] = f2bf(a.y); o[2] = f2bf(a.z); o[3] = f2bf(a.w);
        o[4] = f2bf(b.x); o[5] = f2bf(b.y); o[6] = f2bf(b.z); o[7] = f2bf(b.w);
        *(u16x8*)(out + i) = o;
    } else {
        *(u16x8*)(out + i) = *(const u16x8*)((const unsigned short*)in + i);
    }
}

__global__ __launch_bounds__(256) void write_out(
    const unsigned short* __restrict__ src, void* __restrict__ dst,
    int n, const int* __restrict__ flag)
{
    const int i = (blockIdx.x * 256 + threadIdx.x) * 8;
    if (i >= n) return;
    const u16x8 v = *(const u16x8*)(src + i);
    if (*flag) {
        float4 a, b;
        a.x = bf2f(v[0]); a.y = bf2f(v[1]); a.z = bf2f(v[2]); a.w = bf2f(v[3]);
        b.x = bf2f(v[4]); b.y = bf2f(v[5]); b.z = bf2f(v[6]); b.w = bf2f(v[7]);
        float4* p = (float4*)((float*)dst + i);
        p[0] = a; p[1] = b;
    } else {
        *(u16x8*)((unsigned short*)dst + i) = v;
    }
}

// ---------------------------------------------------------------------------
// Proven 128x128 GEMM: kept for L2 (N=512) and the fallback path.
// ---------------------------------------------------------------------------
template <int RELU, int BIAS, int OUTF, int SWZ>
__global__ __launch_bounds__(256, 2) void gemm_bt(
    const unsigned short* __restrict__ A, const unsigned short* __restrict__ B,
    const float* __restrict__ bias, void* __restrict__ C,
    int M, int N, int K, float alpha,
    long long sA, long long sB, long long sC, const int* __restrict__ flag)
{
    int bxi = blockIdx.x, byi = blockIdx.y;
    if (SWZ) {
        const int id = byi * gridDim.x + bxi;
        bxi = (id >> 3) % gridDim.x;
        byi = (id >> 3) / gridDim.x * 8 + (id & 7);
    }
    const int z = blockIdx.z;
    A += (size_t)z * (size_t)sA;
    B += (size_t)z * (size_t)sB;
    const size_t cofs = (size_t)z * (size_t)sC;

    const int bm = byi * 128;
    const int bn = bxi * 128;
    const int t = threadIdx.x;
    const int lane = t & 63;
    const int w = t >> 6;
    const int wr = (w >> 1) * 64;
    const int wc = (w & 1) * 64;

    __shared__ unsigned short sAt[128 * 32];
    __shared__ unsigned short sBt[128 * 32];

    f32x4 acc[4][4];
#pragma unroll
    for (int i = 0; i < 4; i++)
#pragma unroll
        for (int j = 0; j < 4; j++)
            acc[i][j] = (f32x4){0.f, 0.f, 0.f, 0.f};

    const int tr = t >> 2;
    const int tc = (t & 3) << 3;
    const unsigned short* ga = A + (size_t)(bm + tr) * K + tc;
    const unsigned short* gb = B + (size_t)(bn + tr) * K + tc;
    unsigned short* la = &sAt[tr * 32 + tc];
    unsigned short* lb = &sBt[tr * 32 + tc];

    const int am = wr + (lane & 15);
    const int bn_ = wc + (lane & 15);
    const int ak = (lane >> 4) * 8;

    for (int k0 = 0; k0 < K; k0 += 32) {
        async16(ga, la);
        async16(ga + (size_t)64 * K, la + 64 * 32);
        async16(gb, lb);
        async16(gb + (size_t)64 * K, lb + 64 * 32);
        ga += 32;
        gb += 32;
        __syncthreads();

        bf16x8 af[4], bfr[4];
#pragma unroll
        for (int i = 0; i < 4; i++)
            af[i] = *(const bf16x8*)&sAt[(am + i * 16) * 32 + ak];
#pragma unroll
        for (int j = 0; j < 4; j++)
            bfr[j] = *(const bf16x8*)&sBt[(bn_ + j * 16) * 32 + ak];
#pragma unroll
        for (int i = 0; i < 4; i++)
#pragma unroll
            for (int j = 0; j < 4; j++)
                acc[i][j] = __builtin_amdgcn_mfma_f32_16x16x32_bf16(
                    af[i], bfr[j], acc[i][j], 0, 0, 0);
        __syncthreads();
    }

    const int fl = OUTF ? *flag : 0;
#pragma unroll
    for (int i = 0; i < 4; i++) {
        const int row0 = bm + wr + i * 16 + (lane >> 4) * 4;
#pragma unroll
        for (int j = 0; j < 4; j++) {
            const int col = bn + wc + j * 16 + (lane & 15);
            float bc = 0.f;
            if (BIAS == 1) bc = bias[col];
#pragma unroll
            for (int r = 0; r < 4; r++) {
                float bv = bc;
                if (BIAS == 2) bv = bias[row0 + r];
                float vv = acc[i][j][r] * alpha + bv;
                if (RELU) vv = fmaxf(vv, 0.f);
                const size_t idx = cofs + (size_t)(row0 + r) * N + col;
                if (OUTF && fl) ((float*)C)[idx] = vv;
                else ((unsigned short*)C)[idx] = f2bf(vv);
            }
        }
    }
}

// ---------------------------------------------------------------------------
// R10 gemm8 (proven): 256x256 tile, BK=32, 4 slots, 1 barrier/K-tile.
// SWZ=0: no swizzle. SWZ=1: xy-swizzle within z-slice (thin GEMMs, z=1).
// SWZ=2 (R12): batch->XCD pinning for gridDim.z==8 batched GEMMs: the HW
// dispatches linear block id round-robin over 8 XCDs, so z = h&7 puts all
// of batch z on one XCD; r = h>>3 walks the batch's tiles x-chunked
// (cw<=4..8) y-major so the B-chunk stays L2-resident across y.
// ---------------------------------------------------------------------------
#define G10_STG(SOFS, KOFS) do {                                               \
    async16(gAs + (KOFS), dA + (SOFS));                                        \
    async16(gAs + (KOFS) + rk128, dA + (SOFS) + 4096);                         \
    async16(gBs + (KOFS), dB + (SOFS));                                        \
    async16(gBs + (KOFS) + rk128, dB + (SOFS) + 4096);                         \
} while (0)

template <int RELU, int BIAS, int OUTF, int SWZ>
__global__ __launch_bounds__(512, 2) void gemm8(
    const unsigned short* __restrict__ A, const unsigned short* __restrict__ B,
    const float* __restrict__ bias, void* __restrict__ C,
    int M, int N, int K, float alpha,
    long long sA, long long sB, long long sC, const int* __restrict__ flag)
{
    extern __shared__ unsigned short lds[];
    (void)M;
    int bxi = blockIdx.x, byi = blockIdx.y, z = blockIdx.z;
    if (SWZ == 1) {
        const int id = byi * gridDim.x + bxi;
        bxi = (id >> 3) % gridDim.x;
        byi = (id >> 3) / gridDim.x * 8 + (id & 7);
    } else if (SWZ == 2) {
        const int gx = gridDim.x, gy = gridDim.y;
        const int h = (z * gy + byi) * gx + bxi;
        z = h & 7;
        const int r = h >> 3;
        const int cw = (gx < 4) ? gx : ((32 / gy < gx) ? (32 / gy) : gx);
        const int per = cw * gy;
        const int cg = r / per;
        const int rr = r % per;
        byi = rr / cw;
        bxi = cg * cw + rr % cw;
    }
    A += (size_t)z * (size_t)sA;
    B += (size_t)z * (size_t)sB;
    const size_t cofs = (size_t)z * (size_t)sC;

    const int bm = byi * 256;
    const int bn = bxi * 256;
    const int t = threadIdx.x;
    const int lane = t & 63;
    const int w = t >> 6;
    const int wm = w >> 2;
    const int wn = w & 3;

    const int soct = ((t & 3) ^ ((t >> 3) & 3)) << 3;
    const unsigned short* gAs = A + (size_t)(bm + (t >> 2)) * K + soct;
    const unsigned short* gBs = B + (size_t)(bn + (t >> 2)) * K + soct;
    const size_t rk128 = (size_t)128 * K;
    unsigned short* dA = lds + t * 8;
    unsigned short* dB = lds + 32768 + t * 8;

    const int l15 = lane & 15;
    const int oct = (((lane >> 4) ^ ((lane >> 1) & 3)) << 3);
    const int aoff = (wm * 128 + l15) * 32 + oct;
    const int boff = (wn * 64 + l15) * 32 + oct;

    f32x4 acc[8][4];
#pragma unroll
    for (int i = 0; i < 8; i++)
#pragma unroll
        for (int j = 0; j < 4; j++)
            acc[i][j] = (f32x4){0.f, 0.f, 0.f, 0.f};

    G10_STG(0, 0);
    G10_STG(8192, 32);
    asm volatile("s_waitcnt vmcnt(4)" ::: "memory");
    __builtin_amdgcn_s_barrier();
    asm volatile("" ::: "memory");

    const int NT = K >> 5;
    for (int T = 0; T < NT; ++T) {
        if (T + 2 < NT) {
            const int so = ((T + 2) & 3) * 8192;
            const int ko = (T + 2) << 5;
            G10_STG(so, ko);
        }
        const int sr = (T & 3) * 8192;
        const unsigned short* pa = lds + sr + aoff;
        const unsigned short* pb = lds + 32768 + sr + boff;
        bf16x8 bb[4], a[8];
#pragma unroll
        for (int n = 0; n < 4; n++)
            bb[n] = *(const bf16x8*)(pb + n * 512);
#pragma unroll
        for (int m = 0; m < 8; m++)
            a[m] = *(const bf16x8*)(pa + m * 512);
        __builtin_amdgcn_s_setprio(1);
#pragma unroll
        for (int m = 0; m < 8; m++)
#pragma unroll
            for (int n = 0; n < 4; n++)
                acc[m][n] = __builtin_amdgcn_mfma_f32_16x16x32_bf16(
                    a[m], bb[n], acc[m][n], 0, 0, 0);
        __builtin_amdgcn_s_setprio(0);
        if (T + 1 < NT) {
            if (T + 2 < NT) {
                asm volatile("s_waitcnt vmcnt(4)" ::: "memory");
            } else {
                asm volatile("s_waitcnt vmcnt(0)" ::: "memory");
            }
            __builtin_amdgcn_s_barrier();
            asm volatile("" ::: "memory");
        }
    }

    const int fl = OUTF ? *flag : 0;
#pragma unroll
    for (int mi = 0; mi < 8; mi++) {
        const int row0 = bm + wm * 128 + mi * 16 + (lane >> 4) * 4;
#pragma unroll
        for (int n = 0; n < 4; n++) {
            const int col = bn + wn * 64 + n * 16 + (lane & 15);
            float bc = 0.f;
            if (BIAS == 1) bc = bias[col];
#pragma unroll
            for (int r = 0; r < 4; r++) {
                float bv = bc;
                if (BIAS == 2) bv = bias[row0 + r];
                float vv = acc[mi][n][r] * alpha + bv;
                if (RELU) vv = fmaxf(vv, 0.f);
                const size_t idx = cofs + (size_t)(row0 + r) * N + col;
                if (OUTF && fl) ((float*)C)[idx] = vv;
                else ((unsigned short*)C)[idx] = f2bf(vv);
            }
        }
    }
}

// ---------------------------------------------------------------------------
__global__ __launch_bounds__(256) void softmax_rows(unsigned short* S, int n)
{
    const size_t row = blockIdx.x;
    unsigned short* p = S + row * (size_t)n;
    const int t = threadIdx.x;
    const int lane = t & 63;
    const int wave = t >> 6;

    u16x8 v = *(const u16x8*)(p + t * 8);
    float f[8];
    float m = -3.0e38f;
#pragma unroll
    for (int i = 0; i < 8; i++) {
        f[i] = bf2f(v[i]);
        m = fmaxf(m, f[i]);
    }
#pragma unroll
    for (int off = 32; off; off >>= 1) m = fmaxf(m, __shfl_xor(m, off, 64));
    __shared__ float redm[4];
    if (lane == 0) redm[wave] = m;
    __syncthreads();
    m = fmaxf(fmaxf(redm[0], redm[1]), fmaxf(redm[2], redm[3]));

    float e[8];
    float s = 0.f;
#pragma unroll
    for (int i = 0; i < 8; i++) {
        e[i] = __expf(f[i] - m);
        s += e[i];
    }
#pragma unroll
    for (int off = 32; off; off >>= 1) s += __shfl_xor(s, off, 64);
    __shared__ float reds[4];
    if (lane == 0) reds[wave] = s;
    __syncthreads();
    s = reds[0] + reds[1] + reds[2] + reds[3];
    const float inv = 1.0f / s;

    u16x8 o;
#pragma unroll
    for (int i = 0; i < 8; i++) o[i] = f2bf(e[i] * inv);
    *(u16x8*)(p + t * 8) = o;
}

// ---------------------------------------------------------------------------
extern "C" void kernel_launch(void* const* d_in, const int* in_sizes, int n_in,
                              void* d_out, int out_size, void* d_ws, size_t ws_size,
                              hipStream_t stream)
{
    const void* x  = d_in[0];
    const void* y  = d_in[1];
    const void* W1 = d_in[2];
    const void* b1 = d_in[3];
    const void* W2 = d_in[4];
    const void* b2 = d_in[5];
    const void* W3 = d_in[6];
    const void* b3 = d_in[7];
    const void* W4 = d_in[8];
    const void* b4 = d_in[9];
    const void* Wq = d_in[10];
    const void* bq = d_in[11];
    const void* Wk = d_in[12];
    const void* bk = d_in[13];
    const void* Wv = d_in[14];
    const void* bv = d_in[15];

    int* flag = (int*)d_ws;
    float* fb = (float*)((char*)d_ws + 64);
    unsigned short* arena = (unsigned short*)((char*)d_ws + 64 + 7 * 1024 * 4);
    const size_t baseB = 64 + 7 * 1024 * 4;
    const size_t MEG = 1024ull * 1024ull;

    auto needB = [&](int G, bool direct) -> size_t {
        return baseB + 2ull * ((6 + 16 + (size_t)G * 6 + (direct ? 0 : 16)) * MEG);
    };
    int G; bool direct;
    if (ws_size >= needB(8, true))      { G = 8; direct = true;  }
    else if (ws_size >= needB(4, false)) { G = 4; direct = false; }
    else if (ws_size >= needB(2, false)) { G = 2; direct = false; }
    else                                 { G = 1; direct = false; }

    unsigned short* W1t = arena;
    unsigned short* W2t = W1t + 1 * MEG;
    unsigned short* W3t = W2t + MEG / 2;
    unsigned short* W4t = W3t + MEG / 2;
    unsigned short* Wqt = W4t + 1 * MEG;
    unsigned short* Wkt = Wqt + 1 * MEG;
    unsigned short* Wvt = Wkt + 1 * MEG;
    unsigned short* XC  = Wvt + 1 * MEG;
    unsigned short* VT  = XC + 16 * MEG;
    unsigned short* SBUF = VT + (size_t)G * 2 * MEG;
    unsigned short* OUTS = SBUF + (size_t)G * 4 * MEG;

    unsigned short* PA = (unsigned short*)d_out;
    unsigned short* PB = PA + 16 * MEG;

    float* fb1 = fb;
    float* fb2 = fb + 1024;
    float* fb3 = fb + 2048;
    float* fb4 = fb + 3072;
    float* fbq = fb + 4096;
    float* fbk = fb + 5120;
    float* fbv = fb + 6144;

    const dim3 blk(256);
    const dim3 blk8(512);
    const int LDS8 = 131072;
    const int NE = 16 * 1024 * 1024;
    const int Mx = 16384;
    const long long Z0 = 0;
    const long long sQK = 2048ll * 1024;
    const long long sS  = 2048ll * 2048;

    (void)hipFuncSetAttribute((const void*)&gemm8<1, 1, 0, 1>,
                              hipFuncAttributeMaxDynamicSharedMemorySize, LDS8);
    (void)hipFuncSetAttribute((const void*)&gemm8<0, 1, 0, 1>,
                              hipFuncAttributeMaxDynamicSharedMemorySize, LDS8);
    (void)hipFuncSetAttribute((const void*)&gemm8<0, 2, 0, 2>,
                              hipFuncAttributeMaxDynamicSharedMemorySize, LDS8);
    (void)hipFuncSetAttribute((const void*)&gemm8<0, 0, 0, 2>,
                              hipFuncAttributeMaxDynamicSharedMemorySize, LDS8);
    (void)hipFuncSetAttribute((const void*)&gemm8<0, 0, 1, 2>,
                              hipFuncAttributeMaxDynamicSharedMemorySize, LDS8);

    detect_dtype<<<1, 64, 0, stream>>>((const unsigned short*)W1, flag);
    conv_bias_all<<<28, blk, 0, stream>>>(b1, b2, b3, b4, bq, bk, bv, fb, flag);
    conv_weight_t7<<<dim3(32, 32, 7), blk, 0, stream>>>(
        W1, W1t, W4, W4t, Wq, Wqt, Wk, Wkt, Wv, Wvt, W2, W2t, W3, W3t, flag);

    conv_to_bf16<<<8192, blk, 0, stream>>>(x, XC, NE, flag);

    // MLP: L1/L3/L4 on gemm8 (256x256), L2 (N=512) on proven gemm_bt
    gemm8<1, 1, 0, 1><<<dim3(4, 64), blk8, LDS8, stream>>>(
        XC, W1t, fb1, PA, Mx, 1024, 1024, 1.f, Z0, Z0, Z0, flag);
    gemm_bt<1, 1, 0, 1><<<dim3(4, 128), blk, 0, stream>>>(
        PA, W2t, fb2, PB, Mx, 512, 1024, 1.f, Z0, Z0, Z0, flag);
    gemm8<1, 1, 0, 1><<<dim3(4, 64), blk8, LDS8, stream>>>(
        PB, W3t, fb3, PA, Mx, 1024, 512, 1.f, Z0, Z0, Z0, flag);
    gemm8<1, 1, 0, 1><<<dim3(4, 64), blk8, LDS8, stream>>>(
        PA, W4t, fb4, PB, Mx, 1024, 1024, 1.f, Z0, Z0, Z0, flag);

    // q -> PA ; y -> XC ; k -> PB
    gemm8<0, 1, 0, 1><<<dim3(4, 64), blk8, LDS8, stream>>>(
        PB, Wqt, fbq, PA, Mx, 1024, 1024, 1.f, Z0, Z0, Z0, flag);
    conv_to_bf16<<<8192, blk, 0, stream>>>(y, XC, NE, flag);
    gemm8<0, 1, 0, 1><<<dim3(4, 64), blk8, LDS8, stream>>>(
        XC, Wkt, fbk, PB, Mx, 1024, 1024, 1.f, Z0, Z0, Z0, flag);

    if (direct) {
        gemm8<0, 2, 0, 2><<<dim3(8, 4, 8), blk8, LDS8, stream>>>(
            Wvt, XC, fbv, VT, 1024, 2048, 1024, 1.f, Z0, sQK, sQK, flag);
        gemm8<0, 0, 0, 2><<<dim3(8, 8, 8), blk8, LDS8, stream>>>(
            PA, PB, nullptr, SBUF, 2048, 2048, 1024, 0.03125f, sQK, sQK, sS, flag);
        softmax_rows<<<dim3(8 * 2048), blk, 0, stream>>>(SBUF, 2048);
        gemm8<0, 0, 1, 2><<<dim3(4, 8, 8), blk8, LDS8, stream>>>(
            SBUF, VT, nullptr, d_out, 2048, 1024, 2048, 1.f, sS, sQK, sQK, flag);
    } else {
        for (int g = 0; g < 8; g += G) {
            const size_t off = (size_t)g * 2048 * 1024;
            gemm_bt<0, 2, 0, 0><<<dim3(16, 8, G), blk, 0, stream>>>(
                Wvt, XC + off, fbv, VT, 1024, 2048, 1024, 1.f, Z0, sQK, sQK, flag);
            gemm_bt<0, 0, 0, 1><<<dim3(16, 16, G), blk, 0, stream>>>(
                PA + off, PB + off, nullptr, SBUF, 2048, 2048, 1024, 0.03125f, sQK, sQK, sS, flag);
            softmax_rows<<<dim3(G * 2048), blk, 0, stream>>>(SBUF, 2048);
            gemm_bt<0, 0, 0, 1><<<dim3(8, 16, G), blk, 0, stream>>>(
                SBUF, VT, nullptr, OUTS + off, 2048, 1024, 2048, 1.f, sS, sQK, sQK, flag);
        }
        write_out<<<8192, blk, 0, stream>>>(OUTS, d_out, NE, flag);
    }
}

// Round 8
// 616.627 us; speedup vs baseline: 1.0343x; 1.0222x over previous
//
#include <hip/hip_runtime.h>
#include <stdint.h>

// CrossAttention, fp32/bf16 I/O autodetect, all-bf16 MFMA pipeline.
// R13: base = R10 (603us, best). Single change: gemm8 LDS 4 slots -> 2
// slots (128KiB -> 64KiB) so TWO blocks co-reside per CU. R6-R12 showed
// the schedule is stall-bound at barriers with 1 block/CU (every variant
// pinned ~36% MfmaUtil); m114-style inter-block overlap is the missing
// filler: when block A drains/barriers, block B's waves issue MFMA.
// Prefetch distance drops to 1 tile (stage T+1 during compute of T,
// vmcnt(0) at phase end) - issue-to-drain ~1200cy covers most of HBM
// latency, co-resident block covers the rest. R12's SWZ=2 XCD-pinning
// retired (fetch -66% but stalls +19%). Everything else identical to R10.

typedef __attribute__((ext_vector_type(8))) short bf16x8;
typedef __attribute__((ext_vector_type(4))) float f32x4;
typedef __attribute__((ext_vector_type(8))) unsigned short u16x8;

__device__ __forceinline__ float bf2f(unsigned short u) {
    return __uint_as_float(((unsigned int)u) << 16);
}
__device__ __forceinline__ unsigned short f2bf(float f) {
    unsigned int u = __float_as_uint(f);
    unsigned int r = (u + 0x7fffu + ((u >> 16) & 1u)) >> 16;
    return (unsigned short)r;
}

__device__ __forceinline__ void async16(const void* g, void* l) {
    __builtin_amdgcn_global_load_lds(
        (const __attribute__((address_space(1))) unsigned int*)g,
        (__attribute__((address_space(3))) unsigned int*)l,
        16, 0, 0);
}

// ---------------------------------------------------------------------------
__global__ __launch_bounds__(64) void detect_dtype(
    const unsigned short* __restrict__ w, int* __restrict__ flag)
{
    const int t = threadIdx.x;
    int cnt = 0;
    for (int i = t; i < 4096; i += 64) {
        const unsigned e = (w[i] >> 7) & 0xFF;
        cnt += (e >= 140) ? 1 : 0;
    }
#pragma unroll
    for (int off = 32; off; off >>= 1) cnt += __shfl_xor(cnt, off, 64);
    if (t == 0) flag[0] = (cnt >= 8) ? 1 : 0;
}

// ---------------------------------------------------------------------------
__global__ __launch_bounds__(256) void conv_bias_all(
    const void* b1, const void* b2, const void* b3, const void* b4,
    const void* bq, const void* bk, const void* bv,
    float* __restrict__ out, const int* __restrict__ flag)
{
    const int i = blockIdx.x * 256 + threadIdx.x;
    const int slot = i >> 10, idx = i & 1023;
    if (slot == 1 && idx >= 512) return;
    const void* src = (slot == 0) ? b1 : (slot == 1) ? b2 : (slot == 2) ? b3 :
                      (slot == 3) ? b4 : (slot == 4) ? bq : (slot == 5) ? bk : bv;
    out[i] = (*flag) ? ((const float*)src)[idx]
                     : bf2f(((const unsigned short*)src)[idx]);
}

// ---------------------------------------------------------------------------
__device__ __forceinline__ void wt_body(
    const void* in, unsigned short* out, int R, int C, int f)
{
    __shared__ unsigned short tile[32][33];
    const int bc = blockIdx.x * 32;
    const int br = blockIdx.y * 32;
    const int x = threadIdx.x & 31;
    const int y = threadIdx.x >> 5;
#pragma unroll
    for (int i = 0; i < 4; i++) {
        const int r = y + i * 8;
        unsigned short v;
        if (f) v = f2bf(((const float*)in)[(size_t)(br + r) * C + bc + x]);
        else   v = ((const unsigned short*)in)[(size_t)(br + r) * C + bc + x];
        tile[r][x] = v;
    }
    __syncthreads();
#pragma unroll
    for (int i = 0; i < 4; i++) {
        const int r = y + i * 8;
        out[(size_t)(bc + r) * R + br + x] = tile[x][r];
    }
}

__global__ __launch_bounds__(256) void conv_weight_t7(
    const void* i0, unsigned short* o0, const void* i1, unsigned short* o1,
    const void* i2, unsigned short* o2, const void* i3, unsigned short* o3,
    const void* i4, unsigned short* o4, const void* i5, unsigned short* o5,
    const void* i6, unsigned short* o6, const int* flag)
{
    const int z = blockIdx.z;
    if (z == 5) {
        if (blockIdx.x >= 16) return;
        wt_body(i5, o5, 1024, 512, *flag);
        return;
    }
    if (z == 6) {
        if (blockIdx.y >= 16) return;
        wt_body(i6, o6, 512, 1024, *flag);
        return;
    }
    const void* in = (z == 0) ? i0 : (z == 1) ? i1 : (z == 2) ? i2 : (z == 3) ? i3 : i4;
    unsigned short* out = (z == 0) ? o0 : (z == 1) ? o1 : (z == 2) ? o2 : (z == 3) ? o3 : o4;
    wt_body(in, out, 1024, 1024, *flag);
}

__global__ __launch_bounds__(256) void conv_to_bf16(
    const void* __restrict__ in, unsigned short* __restrict__ out,
    int n, const int* __restrict__ flag)
{
    const int i = (blockIdx.x * 256 + threadIdx.x) * 8;
    if (i >= n) return;
    if (*flag) {
        const float4* p = (const float4*)((const float*)in + i);
        const float4 a = p[0], b = p[1];
        u16x8 o;
        o[0] = f2bf(a.x); o[1] = f2bf(a.y); o[2] = f2bf(a.z); o[3] = f2bf(a.w);
        o[4] = f2bf(b.x); o[5] = f2bf(b.y); o[6] = f2bf(b.z); o[7] = f2bf(b.w);
        *(u16x8*)(out + i) = o;
    } else {
        *(u16x8*)(out + i) = *(const u16x8*)((const unsigned short*)in + i);
    }
}

__global__ __launch_bounds__(256) void write_out(
    const unsigned short* __restrict__ src, void* __restrict__ dst,
    int n, const int* __restrict__ flag)
{
    const int i = (blockIdx.x * 256 + threadIdx.x) * 8;
    if (i >= n) return;
    const u16x8 v = *(const u16x8*)(src + i);
    if (*flag) {
        float4 a, b;
        a.x = bf2f(v[0]); a.y = bf2f(v[1]); a.z = bf2f(v[2]); a.w = bf2f(v[3]);
        b.x = bf2f(v[4]); b.y = bf2f(v[5]); b.z = bf2f(v[6]); b.w = bf2f(v[7]);
        float4* p = (float4*)((float*)dst + i);
        p[0] = a; p[1] = b;
    } else {
        *(u16x8*)((unsigned short*)dst + i) = v;
    }
}

// ---------------------------------------------------------------------------
// Proven 128x128 GEMM: kept for L2 (N=512) and the fallback path.
// ---------------------------------------------------------------------------
template <int RELU, int BIAS, int OUTF, int SWZ>
__global__ __launch_bounds__(256, 2) void gemm_bt(
    const unsigned short* __restrict__ A, const unsigned short* __restrict__ B,
    const float* __restrict__ bias, void* __restrict__ C,
    int M, int N, int K, float alpha,
    long long sA, long long sB, long long sC, const int* __restrict__ flag)
{
    int bxi = blockIdx.x, byi = blockIdx.y;
    if (SWZ) {
        const int id = byi * gridDim.x + bxi;
        bxi = (id >> 3) % gridDim.x;
        byi = (id >> 3) / gridDim.x * 8 + (id & 7);
    }
    const int z = blockIdx.z;
    A += (size_t)z * (size_t)sA;
    B += (size_t)z * (size_t)sB;
    const size_t cofs = (size_t)z * (size_t)sC;

    const int bm = byi * 128;
    const int bn = bxi * 128;
    const int t = threadIdx.x;
    const int lane = t & 63;
    const int w = t >> 6;
    const int wr = (w >> 1) * 64;
    const int wc = (w & 1) * 64;

    __shared__ unsigned short sAt[128 * 32];
    __shared__ unsigned short sBt[128 * 32];

    f32x4 acc[4][4];
#pragma unroll
    for (int i = 0; i < 4; i++)
#pragma unroll
        for (int j = 0; j < 4; j++)
            acc[i][j] = (f32x4){0.f, 0.f, 0.f, 0.f};

    const int tr = t >> 2;
    const int tc = (t & 3) << 3;
    const unsigned short* ga = A + (size_t)(bm + tr) * K + tc;
    const unsigned short* gb = B + (size_t)(bn + tr) * K + tc;
    unsigned short* la = &sAt[tr * 32 + tc];
    unsigned short* lb = &sBt[tr * 32 + tc];

    const int am = wr + (lane & 15);
    const int bn_ = wc + (lane & 15);
    const int ak = (lane >> 4) * 8;

    for (int k0 = 0; k0 < K; k0 += 32) {
        async16(ga, la);
        async16(ga + (size_t)64 * K, la + 64 * 32);
        async16(gb, lb);
        async16(gb + (size_t)64 * K, lb + 64 * 32);
        ga += 32;
        gb += 32;
        __syncthreads();

        bf16x8 af[4], bfr[4];
#pragma unroll
        for (int i = 0; i < 4; i++)
            af[i] = *(const bf16x8*)&sAt[(am + i * 16) * 32 + ak];
#pragma unroll
        for (int j = 0; j < 4; j++)
            bfr[j] = *(const bf16x8*)&sBt[(bn_ + j * 16) * 32 + ak];
#pragma unroll
        for (int i = 0; i < 4; i++)
#pragma unroll
            for (int j = 0; j < 4; j++)
                acc[i][j] = __builtin_amdgcn_mfma_f32_16x16x32_bf16(
                    af[i], bfr[j], acc[i][j], 0, 0, 0);
        __syncthreads();
    }

    const int fl = OUTF ? *flag : 0;
#pragma unroll
    for (int i = 0; i < 4; i++) {
        const int row0 = bm + wr + i * 16 + (lane >> 4) * 4;
#pragma unroll
        for (int j = 0; j < 4; j++) {
            const int col = bn + wc + j * 16 + (lane & 15);
            float bc = 0.f;
            if (BIAS == 1) bc = bias[col];
#pragma unroll
            for (int r = 0; r < 4; r++) {
                float bv = bc;
                if (BIAS == 2) bv = bias[row0 + r];
                float vv = acc[i][j][r] * alpha + bv;
                if (RELU) vv = fmaxf(vv, 0.f);
                const size_t idx = cofs + (size_t)(row0 + r) * N + col;
                if (OUTF && fl) ((float*)C)[idx] = vv;
                else ((unsigned short*)C)[idx] = f2bf(vv);
            }
        }
    }
}

// ---------------------------------------------------------------------------
// R13 gemm8: 256x256 tile, BK=32, 8 waves, 2 LDS tile-slots of 32 KiB
// (A[2][256x32] at 0..32KiB, B[2][256x32] at 32..64KiB) = 64 KiB total ->
// 2 blocks/CU. Loop per 32-K tile: {stage T+1 -> slot (T+1)&1 | 12
// ds_read_b128 from slot T&1 | 32 MFMA | vmcnt(0) ; barrier}. WAR-safe:
// slot (T+1)&1 was last read in phase T-1, whose reads drained before its
// end-of-phase barrier. Swizzle identical to R10 (verified conflict-free).
// Requires M%256==0, N%256==0, K%32==0, K>=64.
// ---------------------------------------------------------------------------
#define G10_STG(SOFS, KOFS) do {                                               \
    async16(gAs + (KOFS), dA + (SOFS));                                        \
    async16(gAs + (KOFS) + rk128, dA + (SOFS) + 4096);                         \
    async16(gBs + (KOFS), dB + (SOFS));                                        \
    async16(gBs + (KOFS) + rk128, dB + (SOFS) + 4096);                         \
} while (0)

template <int RELU, int BIAS, int OUTF, int SWZ>
__global__ __launch_bounds__(512, 2) void gemm8(
    const unsigned short* __restrict__ A, const unsigned short* __restrict__ B,
    const float* __restrict__ bias, void* __restrict__ C,
    int M, int N, int K, float alpha,
    long long sA, long long sB, long long sC, const int* __restrict__ flag)
{
    extern __shared__ unsigned short lds[];
    (void)M;
    int bxi = blockIdx.x, byi = blockIdx.y;
    if (SWZ) {
        const int id = byi * gridDim.x + bxi;
        bxi = (id >> 3) % gridDim.x;
        byi = (id >> 3) / gridDim.x * 8 + (id & 7);
    }
    const int z = blockIdx.z;
    A += (size_t)z * (size_t)sA;
    B += (size_t)z * (size_t)sB;
    const size_t cofs = (size_t)z * (size_t)sC;

    const int bm = byi * 256;
    const int bn = bxi * 256;
    const int t = threadIdx.x;
    const int lane = t & 63;
    const int w = t >> 6;
    const int wm = w >> 2;
    const int wn = w & 3;

    const int soct = ((t & 3) ^ ((t >> 3) & 3)) << 3;
    const unsigned short* gAs = A + (size_t)(bm + (t >> 2)) * K + soct;
    const unsigned short* gBs = B + (size_t)(bn + (t >> 2)) * K + soct;
    const size_t rk128 = (size_t)128 * K;
    unsigned short* dA = lds + t * 8;            // A slots: + s*8192 (ushorts)
    unsigned short* dB = lds + 16384 + t * 8;    // B slots: + s*8192

    const int l15 = lane & 15;
    const int oct = (((lane >> 4) ^ ((lane >> 1) & 3)) << 3);
    const int aoff = (wm * 128 + l15) * 32 + oct;
    const int boff = (wn * 64 + l15) * 32 + oct;

    f32x4 acc[8][4];
#pragma unroll
    for (int i = 0; i < 8; i++)
#pragma unroll
        for (int j = 0; j < 4; j++)
            acc[i][j] = (f32x4){0.f, 0.f, 0.f, 0.f};

    // prologue: tile0 -> slot0; drain; barrier.
    G10_STG(0, 0);
    asm volatile("s_waitcnt vmcnt(0)" ::: "memory");
    __builtin_amdgcn_s_barrier();
    asm volatile("" ::: "memory");

    const int NT = K >> 5;
    for (int T = 0; T < NT; ++T) {
        if (T + 1 < NT) {
            const int so = ((T + 1) & 1) * 8192;
            const int ko = (T + 1) << 5;
            G10_STG(so, ko);
        }
        const int sr = (T & 1) * 8192;
        const unsigned short* pa = lds + sr + aoff;
        const unsigned short* pb = lds + 16384 + sr + boff;
        bf16x8 bb[4], a[8];
#pragma unroll
        for (int n = 0; n < 4; n++)
            bb[n] = *(const bf16x8*)(pb + n * 512);
#pragma unroll
        for (int m = 0; m < 8; m++)
            a[m] = *(const bf16x8*)(pa + m * 512);
        __builtin_amdgcn_s_setprio(1);
#pragma unroll
        for (int m = 0; m < 8; m++)
#pragma unroll
            for (int n = 0; n < 4; n++)
                acc[m][n] = __builtin_amdgcn_mfma_f32_16x16x32_bf16(
                    a[m], bb[n], acc[m][n], 0, 0, 0);
        __builtin_amdgcn_s_setprio(0);
        if (T + 1 < NT) {
            asm volatile("s_waitcnt vmcnt(0)" ::: "memory");
            __builtin_amdgcn_s_barrier();
            asm volatile("" ::: "memory");
        }
    }

    const int fl = OUTF ? *flag : 0;
#pragma unroll
    for (int mi = 0; mi < 8; mi++) {
        const int row0 = bm + wm * 128 + mi * 16 + (lane >> 4) * 4;
#pragma unroll
        for (int n = 0; n < 4; n++) {
            const int col = bn + wn * 64 + n * 16 + (lane & 15);
            float bc = 0.f;
            if (BIAS == 1) bc = bias[col];
#pragma unroll
            for (int r = 0; r < 4; r++) {
                float bv = bc;
                if (BIAS == 2) bv = bias[row0 + r];
                float vv = acc[mi][n][r] * alpha + bv;
                if (RELU) vv = fmaxf(vv, 0.f);
                const size_t idx = cofs + (size_t)(row0 + r) * N + col;
                if (OUTF && fl) ((float*)C)[idx] = vv;
                else ((unsigned short*)C)[idx] = f2bf(vv);
            }
        }
    }
}

// ---------------------------------------------------------------------------
__global__ __launch_bounds__(256) void softmax_rows(unsigned short* S, int n)
{
    const size_t row = blockIdx.x;
    unsigned short* p = S + row * (size_t)n;
    const int t = threadIdx.x;
    const int lane = t & 63;
    const int wave = t >> 6;

    u16x8 v = *(const u16x8*)(p + t * 8);
    float f[8];
    float m = -3.0e38f;
#pragma unroll
    for (int i = 0; i < 8; i++) {
        f[i] = bf2f(v[i]);
        m = fmaxf(m, f[i]);
    }
#pragma unroll
    for (int off = 32; off; off >>= 1) m = fmaxf(m, __shfl_xor(m, off, 64));
    __shared__ float redm[4];
    if (lane == 0) redm[wave] = m;
    __syncthreads();
    m = fmaxf(fmaxf(redm[0], redm[1]), fmaxf(redm[2], redm[3]));

    float e[8];
    float s = 0.f;
#pragma unroll
    for (int i = 0; i < 8; i++) {
        e[i] = __expf(f[i] - m);
        s += e[i];
    }
#pragma unroll
    for (int off = 32; off; off >>= 1) s += __shfl_xor(s, off, 64);
    __shared__ float reds[4];
    if (lane == 0) reds[wave] = s;
    __syncthreads();
    s = reds[0] + reds[1] + reds[2] + reds[3];
    const float inv = 1.0f / s;

    u16x8 o;
#pragma unroll
    for (int i = 0; i < 8; i++) o[i] = f2bf(e[i] * inv);
    *(u16x8*)(p + t * 8) = o;
}

// ---------------------------------------------------------------------------
extern "C" void kernel_launch(void* const* d_in, const int* in_sizes, int n_in,
                              void* d_out, int out_size, void* d_ws, size_t ws_size,
                              hipStream_t stream)
{
    const void* x  = d_in[0];
    const void* y  = d_in[1];
    const void* W1 = d_in[2];
    const void* b1 = d_in[3];
    const void* W2 = d_in[4];
    const void* b2 = d_in[5];
    const void* W3 = d_in[6];
    const void* b3 = d_in[7];
    const void* W4 = d_in[8];
    const void* b4 = d_in[9];
    const void* Wq = d_in[10];
    const void* bq = d_in[11];
    const void* Wk = d_in[12];
    const void* bk = d_in[13];
    const void* Wv = d_in[14];
    const void* bv = d_in[15];

    int* flag = (int*)d_ws;
    float* fb = (float*)((char*)d_ws + 64);
    unsigned short* arena = (unsigned short*)((char*)d_ws + 64 + 7 * 1024 * 4);
    const size_t baseB = 64 + 7 * 1024 * 4;
    const size_t MEG = 1024ull * 1024ull;

    auto needB = [&](int G, bool direct) -> size_t {
        return baseB + 2ull * ((6 + 16 + (size_t)G * 6 + (direct ? 0 : 16)) * MEG);
    };
    int G; bool direct;
    if (ws_size >= needB(8, true))      { G = 8; direct = true;  }
    else if (ws_size >= needB(4, false)) { G = 4; direct = false; }
    else if (ws_size >= needB(2, false)) { G = 2; direct = false; }
    else                                 { G = 1; direct = false; }

    unsigned short* W1t = arena;
    unsigned short* W2t = W1t + 1 * MEG;
    unsigned short* W3t = W2t + MEG / 2;
    unsigned short* W4t = W3t + MEG / 2;
    unsigned short* Wqt = W4t + 1 * MEG;
    unsigned short* Wkt = Wqt + 1 * MEG;
    unsigned short* Wvt = Wkt + 1 * MEG;
    unsigned short* XC  = Wvt + 1 * MEG;
    unsigned short* VT  = XC + 16 * MEG;
    unsigned short* SBUF = VT + (size_t)G * 2 * MEG;
    unsigned short* OUTS = SBUF + (size_t)G * 4 * MEG;

    unsigned short* PA = (unsigned short*)d_out;
    unsigned short* PB = PA + 16 * MEG;

    float* fb1 = fb;
    float* fb2 = fb + 1024;
    float* fb3 = fb + 2048;
    float* fb4 = fb + 3072;
    float* fbq = fb + 4096;
    float* fbk = fb + 5120;
    float* fbv = fb + 6144;

    const dim3 blk(256);
    const dim3 blk8(512);
    const int LDS8 = 65536;
    const int NE = 16 * 1024 * 1024;
    const int Mx = 16384;
    const long long Z0 = 0;
    const long long sQK = 2048ll * 1024;
    const long long sS  = 2048ll * 2048;

    (void)hipFuncSetAttribute((const void*)&gemm8<1, 1, 0, 1>,
                              hipFuncAttributeMaxDynamicSharedMemorySize, LDS8);
    (void)hipFuncSetAttribute((const void*)&gemm8<0, 1, 0, 1>,
                              hipFuncAttributeMaxDynamicSharedMemorySize, LDS8);
    (void)hipFuncSetAttribute((const void*)&gemm8<0, 2, 0, 0>,
                              hipFuncAttributeMaxDynamicSharedMemorySize, LDS8);
    (void)hipFuncSetAttribute((const void*)&gemm8<0, 0, 0, 1>,
                              hipFuncAttributeMaxDynamicSharedMemorySize, LDS8);
    (void)hipFuncSetAttribute((const void*)&gemm8<0, 0, 1, 1>,
                              hipFuncAttributeMaxDynamicSharedMemorySize, LDS8);

    detect_dtype<<<1, 64, 0, stream>>>((const unsigned short*)W1, flag);
    conv_bias_all<<<28, blk, 0, stream>>>(b1, b2, b3, b4, bq, bk, bv, fb, flag);
    conv_weight_t7<<<dim3(32, 32, 7), blk, 0, stream>>>(
        W1, W1t, W4, W4t, Wq, Wqt, Wk, Wkt, Wv, Wvt, W2, W2t, W3, W3t, flag);

    conv_to_bf16<<<8192, blk, 0, stream>>>(x, XC, NE, flag);

    // MLP: L1/L3/L4 on gemm8 (256x256), L2 (N=512) on proven gemm_bt
    gemm8<1, 1, 0, 1><<<dim3(4, 64), blk8, LDS8, stream>>>(
        XC, W1t, fb1, PA, Mx, 1024, 1024, 1.f, Z0, Z0, Z0, flag);
    gemm_bt<1, 1, 0, 1><<<dim3(4, 128), blk, 0, stream>>>(
        PA, W2t, fb2, PB, Mx, 512, 1024, 1.f, Z0, Z0, Z0, flag);
    gemm8<1, 1, 0, 1><<<dim3(4, 64), blk8, LDS8, stream>>>(
        PB, W3t, fb3, PA, Mx, 1024, 512, 1.f, Z0, Z0, Z0, flag);
    gemm8<1, 1, 0, 1><<<dim3(4, 64), blk8, LDS8, stream>>>(
        PA, W4t, fb4, PB, Mx, 1024, 1024, 1.f, Z0, Z0, Z0, flag);

    // q -> PA ; y -> XC ; k -> PB
    gemm8<0, 1, 0, 1><<<dim3(4, 64), blk8, LDS8, stream>>>(
        PB, Wqt, fbq, PA, Mx, 1024, 1024, 1.f, Z0, Z0, Z0, flag);
    conv_to_bf16<<<8192, blk, 0, stream>>>(y, XC, NE, flag);
    gemm8<0, 1, 0, 1><<<dim3(4, 64), blk8, LDS8, stream>>>(
        XC, Wkt, fbk, PB, Mx, 1024, 1024, 1.f, Z0, Z0, Z0, flag);

    if (direct) {
        gemm8<0, 2, 0, 0><<<dim3(8, 4, 8), blk8, LDS8, stream>>>(
            Wvt, XC, fbv, VT, 1024, 2048, 1024, 1.f, Z0, sQK, sQK, flag);
        gemm8<0, 0, 0, 1><<<dim3(8, 8, 8), blk8, LDS8, stream>>>(
            PA, PB, nullptr, SBUF, 2048, 2048, 1024, 0.03125f, sQK, sQK, sS, flag);
        softmax_rows<<<dim3(8 * 2048), blk, 0, stream>>>(SBUF, 2048);
        gemm8<0, 0, 1, 1><<<dim3(4, 8, 8), blk8, LDS8, stream>>>(
            SBUF, VT, nullptr, d_out, 2048, 1024, 2048, 1.f, sS, sQK, sQK, flag);
    } else {
        for (int g = 0; g < 8; g += G) {
            const size_t off = (size_t)g * 2048 * 1024;
            gemm_bt<0, 2, 0, 0><<<dim3(16, 8, G), blk, 0, stream>>>(
                Wvt, XC + off, fbv, VT, 1024, 2048, 1024, 1.f, Z0, sQK, sQK, flag);
            gemm_bt<0, 0, 0, 1><<<dim3(16, 16, G), blk, 0, stream>>>(
                PA + off, PB + off, nullptr, SBUF, 2048, 2048, 1024, 0.03125f, sQK, sQK, sS, flag);
            softmax_rows<<<dim3(G * 2048), blk, 0, stream>>>(SBUF, 2048);
            gemm_bt<0, 0, 0, 1><<<dim3(8, 16, G), blk, 0, stream>>>(
                SBUF, VT, nullptr, OUTS + off, 2048, 1024, 2048, 1.f, sS, sQK, sQK, flag);
        }
        write_out<<<8192, blk, 0, stream>>>(OUTS, d_out, NE, flag);
    }
}